// Round 10
// baseline (335.887 us; speedup 1.0000x reference)
//
#include <hip/hip_runtime.h>
#include <hip/hip_bf16.h>
#include <math.h>

#define BATCH 8
#define SEQ 2048
#define EMBED 1024
#define HEAD 64
#define NROWS (BATCH*SEQ)   // 16384

typedef short bf16x8 __attribute__((ext_vector_type(8)));
typedef short bf16x4 __attribute__((ext_vector_type(4)));
typedef float f32x4  __attribute__((ext_vector_type(4)));

__device__ inline short f2bf(float f) {
    __hip_bfloat16 h = __float2bfloat16(f);
    return *(short*)&h;
}
__device__ inline float bf2f(short s) {
    __hip_bfloat16 h = *(__hip_bfloat16*)&s;
    return __bfloat162float(h);
}

// 128-row q-tiles (t=0..15): segments(t) = (t>>1)+1 (4-chunk segments).
// Dense slot offset: triOff128(t) = (g+r)*(g+1), g=t>>1, r=t&1. 72 slots/batch.
#define NSLOT128 72
__device__ inline int triOff128(int t) {
    int g = t >> 1, r = t & 1;
    return (g + r) * (g + 1);
}

// ---------------------------------------------------------------------------
// Kernel 0: W -> bf16 B-fragment order for 16x16x32 MFMA; also zeroes the
// split-K fixup counters (ws is re-poisoned 0xAA before every launch).
// ---------------------------------------------------------------------------
__global__ __launch_bounds__(256) void prep_w(
    const float* __restrict__ Wq, const float* __restrict__ Wk,
    const float* __restrict__ Wv, short* __restrict__ wt, int* __restrict__ cnt)
{
    int g    = blockIdx.x * 256 + threadIdx.x;   // 24576 total
    if (g < BATCH * 16) cnt[g] = 0;
    int lane = g & 63;
    int frag = g >> 6;           // ct*32 + k32
    int k32  = frag & 31;
    int ct   = frag >> 5;        // 0..11
    int col  = ct * 16 + (lane & 15);
    int mm   = col >> 6, cc = col & 63;
    const float* W = (mm == 0) ? Wq : ((mm == 1) ? Wk : Wv);
    int kb = k32 * 32 + (lane >> 4) * 8;
    bf16x8 o;
#pragma unroll
    for (int j = 0; j < 8; j++)
        o[j] = f2bf(W[(size_t)(kb + j) * HEAD + cc]);
    *(bf16x8*)&wt[(size_t)g * 8] = o;
}

// ---------------------------------------------------------------------------
// Kernel 1: QKV projection (single-stage slab). V written TRANSPOSED per
// batch: vt[b][h][t] so attention PV frags are contiguous. Unchanged.
// ---------------------------------------------------------------------------
__global__ __launch_bounds__(512, 4) void proj_kernel(
    const float* __restrict__ x, const short* __restrict__ wt,
    short* __restrict__ q, short* __restrict__ k, short* __restrict__ vt)
{
    __shared__ short xs[32][1024];   // 64 KB, XOR-swizzled k8 blocks
    float* psum = (float*)&xs[0][0]; // 24 KB reuse after compute barrier

    const int tid  = threadIdx.x;
    const int wave = tid >> 6, lane = tid & 63;
    const int m16  = lane & 15, quad = lane >> 4;
    const int cg   = wave & 3;       // col group: ct = cg*3 + j
    const int kh   = wave >> 2;      // k half
    const int r0   = blockIdx.x * 32;

    // ---- stage x slab: 32 rows x 1024, fp32 -> bf16, swizzled ----
    {
        const int row  = tid >> 4;   // 0..31
        const int col4 = tid & 15;   // 0..15
        const float* xr = x + (size_t)(r0 + row) * EMBED;
#pragma unroll
        for (int h = 0; h < 2; h++) {
            float4 f[8];
#pragma unroll
            for (int i = 0; i < 8; i++)
                f[i] = *(const float4*)&xr[(h * 8 + i) * 64 + col4 * 4];
#pragma unroll
            for (int i = 0; i < 8; i++) {
                int c  = (h * 8 + i) * 64 + col4 * 4;
                int k8 = c >> 3, rem = c & 7;
                int cs = ((k8 ^ (row & 7)) << 3) + rem;
                bf16x4 bv;
                bv[0] = f2bf(f[i].x); bv[1] = f2bf(f[i].y);
                bv[2] = f2bf(f[i].z); bv[3] = f2bf(f[i].w);
                *(bf16x4*)&xs[row][cs] = bv;
            }
        }
    }
    __syncthreads();

    // ---- compute: 16 k32 steps x (2 m-tiles x 3 col-tiles) ----
    f32x4 acc[2][3];
#pragma unroll
    for (int mt = 0; mt < 2; mt++)
#pragma unroll
        for (int j = 0; j < 3; j++) acc[mt][j] = (f32x4){0.f, 0.f, 0.f, 0.f};

#pragma unroll 4
    for (int s = 0; s < 16; s++) {
        int k32  = kh * 16 + s;
        int ksw  = ((k32 * 4 + quad) ^ (m16 & 7)) << 3;
        bf16x8 a0 = *(const bf16x8*)&xs[m16][ksw];
        bf16x8 a1 = *(const bf16x8*)&xs[16 + m16][ksw];
#pragma unroll
        for (int j = 0; j < 3; j++) {
            int ct = cg * 3 + j;
            bf16x8 bb = *(const bf16x8*)&wt[(size_t)((ct * 32 + k32) * 64 + lane) * 8];
            acc[0][j] = __builtin_amdgcn_mfma_f32_16x16x32_bf16(a0, bb, acc[0][j], 0, 0, 0);
            acc[1][j] = __builtin_amdgcn_mfma_f32_16x16x32_bf16(a1, bb, acc[1][j], 0, 0, 0);
        }
    }

    // ---- k-split reduce via LDS psum, then store ----
    __syncthreads();
    if (kh == 1) {
        float* p = psum + ((size_t)(cg * 64 + lane) * 24);
#pragma unroll
        for (int mt = 0; mt < 2; mt++)
#pragma unroll
            for (int j = 0; j < 3; j++)
                *(f32x4*)&p[(mt * 3 + j) * 4] = acc[mt][j];
    }
    __syncthreads();
    if (kh == 0) {
        const float* p = psum + ((size_t)(cg * 64 + lane) * 24);
        const int bb = r0 >> 11;          // batch
        const int tb = r0 & 2047;         // batch-local token base
#pragma unroll
        for (int mt = 0; mt < 2; mt++)
#pragma unroll
            for (int j = 0; j < 3; j++) {
                f32x4 o = acc[mt][j] + *(const f32x4*)&p[(mt * 3 + j) * 4];
                int gcol = (cg * 3 + j) * 16 + m16;
                int mm = gcol >> 6, cc = gcol & 63;
                if (mm < 2) {
                    short* op = (mm == 0) ? q : k;
#pragma unroll
                    for (int reg = 0; reg < 4; reg++) {
                        int row = r0 + mt * 16 + quad * 4 + reg;
                        op[(size_t)row * HEAD + cc] = f2bf(o[reg]);
                    }
                } else {
                    bf16x4 pk;
                    pk[0] = f2bf(o[0]); pk[1] = f2bf(o[1]);
                    pk[2] = f2bf(o[2]); pk[3] = f2bf(o[3]);
                    int t = tb + mt * 16 + quad * 4;
                    *(bf16x4*)&vt[(((size_t)bb * 64 + cc) << 11) + t] = pk;
                }
            }
    }
}

// ---------------------------------------------------------------------------
// Kernel 2: staged split-K flash attention, 8-wave sharing, FUSED split-K
// fixup (CUTLASS-style): dense grid (72 slots x 8 batches), every block
// writes its partials, device-fence + atomicAdd on cnt[b][t]; the last
// arriving block combines (own partials kept in fp32 registers; other slots
// read back) and writes out directly. No separate combine dispatch.
// ---------------------------------------------------------------------------
__global__ __launch_bounds__(512, 4) void attn_kernel(
    const short* __restrict__ qg, const short* __restrict__ kg,
    const short* __restrict__ vtg,
    short* __restrict__ pO, float* __restrict__ pl,
    int* __restrict__ cnt, float* __restrict__ out)
{
    __shared__ short ksh[64][72];      // [t][h]
    __shared__ short vsh[64][72];      // [h][t] (from vt, natural)
    __shared__ short psh[8][16][72];   // [wave][row][t], wave-private
    __shared__ int isLast;

    const int s = blockIdx.x;          // dense slot 0..71
    const int b = blockIdx.y;
    // invert dense slot -> (t, seg)
    int t = 0;
    while (t < 15 && s >= triOff128(t + 1)) t++;
    const int seg = s - triOff128(t);
    const int ns  = (t >> 1) + 1;
    const int c0  = seg * 4;
    const int c1  = min(c0 + 4, 2 * t + 2);

    const int tid  = threadIdx.x;
    const int wave = tid >> 6, lane = tid & 63;
    const int m16  = lane & 15, quad = lane >> 4;
    const int qtile = t * 8 + wave;    // 16-row tile, 0..127
    const int own   = qtile >> 2;      // this wave's diagonal chunk
    const float scale = 0.03125f;      // 1024^-0.5

    const short* qb  = qg  + (size_t)b * SEQ * HEAD;
    const short* kb  = kg  + (size_t)b * SEQ * HEAD;
    const short* vtb = vtg + (size_t)b * HEAD * SEQ;

    bf16x8 a_q0, a_q1;
    {
        const int qrow = qtile * 16 + m16;
        a_q0 = *(const bf16x8*)&qb[(size_t)qrow * HEAD + quad * 8];
        a_q1 = *(const bf16x8*)&qb[(size_t)qrow * HEAD + 32 + quad * 8];
    }

    f32x4 o_acc[4];
#pragma unroll
    for (int i = 0; i < 4; i++) o_acc[i] = (f32x4){0.f, 0.f, 0.f, 0.f};
    float lsum[4] = {0.f, 0.f, 0.f, 0.f};

    // staging: thread owns one 16B segment of K and one of V
    const int srow = tid >> 3;         // 0..63
    const int sc8  = (tid & 7) * 8;    // 0..56

    bf16x8 kr = *(const bf16x8*)&kb[(size_t)(c0 * 64 + srow) * HEAD + sc8];
    bf16x8 vr = *(const bf16x8*)&vtb[((size_t)srow << 11) + c0 * 64 + sc8];

    for (int c = c0; c < c1; c++) {
        const int t0 = c * 64;
        __syncthreads();               // barrier A: prev-iter LDS readers done
        *(bf16x8*)&ksh[srow][sc8] = kr;
        *(bf16x8*)&vsh[srow][sc8] = vr;
        __syncthreads();               // barrier B: stores visible
        if (c + 1 < c1) {              // prefetch next chunk (overlaps compute)
            const int tn = (c + 1) * 64;
            kr = *(const bf16x8*)&kb[(size_t)(tn + srow) * HEAD + sc8];
            vr = *(const bf16x8*)&vtb[((size_t)srow << 11) + tn + sc8];
        }
        if (c > own) continue;         // wave past its causal range: barrier-only

        // ---- QK^T from LDS ----
        f32x4 s_t[4];
#pragma unroll
        for (int nt = 0; nt < 4; nt++) {
            bf16x8 bk0 = *(const bf16x8*)&ksh[nt * 16 + m16][quad * 8];
            bf16x8 bk1 = *(const bf16x8*)&ksh[nt * 16 + m16][32 + quad * 8];
            f32x4 acc = (f32x4){0.f, 0.f, 0.f, 0.f};
            acc = __builtin_amdgcn_mfma_f32_16x16x32_bf16(a_q0, bk0, acc, 0, 0, 0);
            acc = __builtin_amdgcn_mfma_f32_16x16x32_bf16(a_q1, bk1, acc, 0, 0, 0);
            s_t[nt] = acc;
        }

        // ---- no-max softmax; mask only on the diagonal chunk ----
        if (c == own) {
#pragma unroll
            for (int r = 0; r < 4; r++) {
                const int row = qtile * 16 + quad * 4 + r;
#pragma unroll
                for (int nt = 0; nt < 4; nt++) {
                    int tt = t0 + nt * 16 + m16;
                    float p = (tt <= row) ? __expf(s_t[nt][r] * scale) : 0.f;
                    lsum[r] += p;
                    psh[wave][quad * 4 + r][nt * 16 + m16] = f2bf(p);
                }
            }
        } else {
#pragma unroll
            for (int r = 0; r < 4; r++) {
#pragma unroll
                for (int nt = 0; nt < 4; nt++) {
                    float p = __expf(s_t[nt][r] * scale);
                    lsum[r] += p;
                    psh[wave][quad * 4 + r][nt * 16 + m16] = f2bf(p);
                }
            }
        }
        // psh wave-private: in-wave LDS ordering suffices, no barrier.

        // ---- PV: B-frags natural from vsh[h][t] ----
#pragma unroll
        for (int ss = 0; ss < 2; ss++) {
            bf16x8 a_p = *(const bf16x8*)&psh[wave][m16][ss * 32 + quad * 8];
#pragma unroll
            for (int ht = 0; ht < 4; ht++) {
                bf16x8 b_v = *(const bf16x8*)&vsh[ht * 16 + m16][ss * 32 + quad * 8];
                o_acc[ht] = __builtin_amdgcn_mfma_f32_16x16x32_bf16(a_p, b_v, o_acc[ht], 0, 0, 0);
            }
        }
    }

    // ---- reduce l over the 16 token-columns ----
#pragma unroll
    for (int r = 0; r < 4; r++) {
#pragma unroll
        for (int off = 8; off >= 1; off >>= 1)
            lsum[r] += __shfl_xor(lsum[r], off, 64);
    }

    // ---- write partials at dense slot (b, s) ----
    const size_t base  = (size_t)b * NSLOT128 + triOff128(t);
    const size_t pbase = ((size_t)b * NSLOT128 + s) * 128;
#pragma unroll
    for (int ht = 0; ht < 4; ht++) {
#pragma unroll
        for (int r = 0; r < 4; r++) {
            int rowt = wave * 16 + quad * 4 + r;
            pO[(pbase + rowt) * 64 + ht * 16 + m16] = f2bf(o_acc[ht][r]);
        }
    }
    if (m16 == 0) {
#pragma unroll
        for (int r = 0; r < 4; r++) {
            int rowt = wave * 16 + quad * 4 + r;
            pl[pbase + rowt] = lsum[r];
        }
    }

    // ---- split-K fixup: last block for (b,t) combines ----
    __threadfence();                   // release partials (device scope)
    __syncthreads();
    if (tid == 0) {
        int old = atomicAdd(&cnt[b * 16 + t], 1);
        isLast = (old == ns - 1);
    }
    __syncthreads();
    if (!isLast) return;
    __threadfence();                   // acquire other blocks' partials

#pragma unroll
    for (int r = 0; r < 4; r++) {
        const int rowt = wave * 16 + quad * 4 + r;
        float L = lsum[r];
        for (int s2 = 0; s2 < ns; s2++) {
            if (s2 == seg) continue;
            L += pl[(base + s2) * 128 + rowt];
        }
        const float invL = 1.f / L;
#pragma unroll
        for (int ht = 0; ht < 4; ht++) {
            float O = o_acc[ht][r];
            for (int s2 = 0; s2 < ns; s2++) {
                if (s2 == seg) continue;
                O += bf2f(pO[((base + s2) * 128 + rowt) * 64 + ht * 16 + m16]);
            }
            out[(((size_t)b * SEQ) + t * 128 + rowt) * HEAD + ht * 16 + m16] = O * invL;
        }
    }
}

// ---------------------------------------------------------------------------
extern "C" void kernel_launch(void* const* d_in, const int* in_sizes, int n_in,
                              void* d_out, int out_size, void* d_ws, size_t ws_size,
                              hipStream_t stream) {
    const float* x  = (const float*)d_in[0];
    const float* Wq = (const float*)d_in[1];
    const float* Wk = (const float*)d_in[2];
    const float* Wv = (const float*)d_in[3];
    float* out = (float*)d_out;

    short* q  = (short*)d_ws;                       // 1,048,576
    short* k  = q + (size_t)NROWS * HEAD;           // 1,048,576
    short* vt = k + (size_t)NROWS * HEAD;           // 1,048,576 (transposed)
    short* wt = vt + (size_t)NROWS * HEAD;          //   196,608
    short* pO = wt + 196608;                        // 8*72*128*64 = 4,718,592
    float* pl = (float*)(pO + (size_t)BATCH * NSLOT128 * 128 * 64);  // 73,728
    int*  cnt = (int*)(pl + (size_t)BATCH * NSLOT128 * 128);         // 128

    prep_w<<<96, 256, 0, stream>>>(Wq, Wk, Wv, wt, cnt);
    proj_kernel<<<512, 512, 0, stream>>>(x, wt, q, k, vt);
    attn_kernel<<<dim3(NSLOT128, BATCH), 512, 0, stream>>>(q, k, vt, pO, pl, cnt, out);
}

// Round 11
// 133.233 us; speedup vs baseline: 2.5210x; 2.5210x over previous
//
#include <hip/hip_runtime.h>
#include <hip/hip_bf16.h>
#include <math.h>

#define BATCH 8
#define SEQ 2048
#define EMBED 1024
#define HEAD 64
#define NROWS (BATCH*SEQ)   // 16384

typedef short bf16x8 __attribute__((ext_vector_type(8)));
typedef short bf16x4 __attribute__((ext_vector_type(4)));
typedef float f32x4  __attribute__((ext_vector_type(4)));

__device__ inline short f2bf(float f) {
    __hip_bfloat16 h = __float2bfloat16(f);
    return *(short*)&h;
}
__device__ inline float bf2f(short s) {
    __hip_bfloat16 h = *(__hip_bfloat16*)&s;
    return __bfloat162float(h);
}

// Dense triangular slots, 64-row qt tiles, 4-chunk segments:
// slots(qt) = (qt>>2)+1; triOff(qt) = 2g(g+1)+(qt&3)(g+1), g=qt>>2. 144/batch.
#define NSLOT 144
__device__ __host__ inline int triOff(int qt) {
    int g = qt >> 2;
    return 2 * g * (g + 1) + (qt & 3) * (g + 1);
}

// ---------------------------------------------------------------------------
// Kernel 0: W -> bf16 B-fragment order for 16x16x32 MFMA.
// ---------------------------------------------------------------------------
__global__ __launch_bounds__(256) void prep_w(
    const float* __restrict__ Wq, const float* __restrict__ Wk,
    const float* __restrict__ Wv, short* __restrict__ wt)
{
    int g    = blockIdx.x * 256 + threadIdx.x;   // 24576 total
    int lane = g & 63;
    int frag = g >> 6;           // ct*32 + k32
    int k32  = frag & 31;
    int ct   = frag >> 5;        // 0..11
    int col  = ct * 16 + (lane & 15);
    int mm   = col >> 6, cc = col & 63;
    const float* W = (mm == 0) ? Wq : ((mm == 1) ? Wk : Wv);
    int kb = k32 * 32 + (lane >> 4) * 8;
    bf16x8 o;
#pragma unroll
    for (int j = 0; j < 8; j++)
        o[j] = f2bf(W[(size_t)(kb + j) * HEAD + cc]);
    *(bf16x8*)&wt[(size_t)g * 8] = o;
}

// ---------------------------------------------------------------------------
// Kernel 1: QKV projection (single-stage slab, proven R7/R9). V written
// TRANSPOSED per batch: vt[b][h][t].
// ---------------------------------------------------------------------------
__global__ __launch_bounds__(512, 4) void proj_kernel(
    const float* __restrict__ x, const short* __restrict__ wt,
    short* __restrict__ q, short* __restrict__ k, short* __restrict__ vt)
{
    __shared__ short xs[32][1024];   // 64 KB, XOR-swizzled k8 blocks
    float* psum = (float*)&xs[0][0]; // reuse after compute barrier

    const int tid  = threadIdx.x;
    const int wave = tid >> 6, lane = tid & 63;
    const int m16  = lane & 15, quad = lane >> 4;
    const int cg   = wave & 3;
    const int kh   = wave >> 2;
    const int r0   = blockIdx.x * 32;

    {
        const int row  = tid >> 4;
        const int col4 = tid & 15;
        const float* xr = x + (size_t)(r0 + row) * EMBED;
#pragma unroll
        for (int h = 0; h < 2; h++) {
            float4 f[8];
#pragma unroll
            for (int i = 0; i < 8; i++)
                f[i] = *(const float4*)&xr[(h * 8 + i) * 64 + col4 * 4];
#pragma unroll
            for (int i = 0; i < 8; i++) {
                int c  = (h * 8 + i) * 64 + col4 * 4;
                int k8 = c >> 3, rem = c & 7;
                int cs = ((k8 ^ (row & 7)) << 3) + rem;
                bf16x4 bv;
                bv[0] = f2bf(f[i].x); bv[1] = f2bf(f[i].y);
                bv[2] = f2bf(f[i].z); bv[3] = f2bf(f[i].w);
                *(bf16x4*)&xs[row][cs] = bv;
            }
        }
    }
    __syncthreads();

    f32x4 acc[2][3];
#pragma unroll
    for (int mt = 0; mt < 2; mt++)
#pragma unroll
        for (int j = 0; j < 3; j++) acc[mt][j] = (f32x4){0.f, 0.f, 0.f, 0.f};

#pragma unroll 4
    for (int s = 0; s < 16; s++) {
        int k32  = kh * 16 + s;
        int ksw  = ((k32 * 4 + quad) ^ (m16 & 7)) << 3;
        bf16x8 a0 = *(const bf16x8*)&xs[m16][ksw];
        bf16x8 a1 = *(const bf16x8*)&xs[16 + m16][ksw];
#pragma unroll
        for (int j = 0; j < 3; j++) {
            int ct = cg * 3 + j;
            bf16x8 bb = *(const bf16x8*)&wt[(size_t)((ct * 32 + k32) * 64 + lane) * 8];
            acc[0][j] = __builtin_amdgcn_mfma_f32_16x16x32_bf16(a0, bb, acc[0][j], 0, 0, 0);
            acc[1][j] = __builtin_amdgcn_mfma_f32_16x16x32_bf16(a1, bb, acc[1][j], 0, 0, 0);
        }
    }

    __syncthreads();
    if (kh == 1) {
        float* p = psum + ((size_t)(cg * 64 + lane) * 24);
#pragma unroll
        for (int mt = 0; mt < 2; mt++)
#pragma unroll
            for (int j = 0; j < 3; j++)
                *(f32x4*)&p[(mt * 3 + j) * 4] = acc[mt][j];
    }
    __syncthreads();
    if (kh == 0) {
        const float* p = psum + ((size_t)(cg * 64 + lane) * 24);
        const int bb = r0 >> 11;
        const int tb = r0 & 2047;
#pragma unroll
        for (int mt = 0; mt < 2; mt++)
#pragma unroll
            for (int j = 0; j < 3; j++) {
                f32x4 o = acc[mt][j] + *(const f32x4*)&p[(mt * 3 + j) * 4];
                int gcol = (cg * 3 + j) * 16 + m16;
                int mm = gcol >> 6, cc = gcol & 63;
                if (mm < 2) {
                    short* op = (mm == 0) ? q : k;
#pragma unroll
                    for (int reg = 0; reg < 4; reg++) {
                        int row = r0 + mt * 16 + quad * 4 + reg;
                        op[(size_t)row * HEAD + cc] = f2bf(o[reg]);
                    }
                } else {
                    bf16x4 pk;
                    pk[0] = f2bf(o[0]); pk[1] = f2bf(o[1]);
                    pk[2] = f2bf(o[2]); pk[3] = f2bf(o[3]);
                    int t = tb + mt * 16 + quad * 4;
                    *(bf16x4*)&vt[(((size_t)bb * 64 + cc) << 11) + t] = pk;
                }
            }
    }
}

// ---------------------------------------------------------------------------
// Kernel 2: split-K flash attention, SINGLE-SLAB staging (R7-proj-style).
// Block = 256 thr = 4 waves = 64 q-rows; seg = 4 KV chunks (256 tokens)
// staged in ONE shot (K natural [t][h]; V natural [h][t] from vt), then ONE
// __syncthreads, then all chunks' QK->softmax->PV with zero further barriers
// (psh wave-private). No-max softmax; diagonal-chunk-only causal mask.
// All staged chunk indices are < 32 so the staging loop has no guards.
// ---------------------------------------------------------------------------
__global__ __launch_bounds__(256, 2) void attn_kernel(
    const short* __restrict__ qg, const short* __restrict__ kg,
    const short* __restrict__ vtg,
    short* __restrict__ pO, float* __restrict__ pl)
{
    __shared__ short ksh[256][72];     // 36 KB  [t'][h], t' = cc*64 + t
    __shared__ short vsh[64][264];     // 33 KB  [h][t']
    __shared__ short psh[4][16][72];   //  9 KB  [wave][row][t], wave-private

    const int qt  = blockIdx.x;        // 0..31 (64-row q tile)
    const int seg = blockIdx.y;        // 0..7
    const int b   = blockIdx.z;
    const int c0  = seg * 4;
    const int c1  = min(c0 + 4, qt + 1);
    if (c0 >= c1) return;
    const int nch = c1 - c0;

    const int tid  = threadIdx.x;
    const int wave = tid >> 6, lane = tid & 63;
    const int m16  = lane & 15, quad = lane >> 4;
    const float scale = 0.03125f;      // 1024^-0.5

    const short* qb  = qg  + (size_t)b * SEQ * HEAD;
    const short* kb  = kg  + (size_t)b * SEQ * HEAD;
    const short* vtb = vtg + (size_t)b * HEAD * SEQ;

    bf16x8 a_q0, a_q1;
    {
        const int qrow = qt * 64 + wave * 16 + m16;
        a_q0 = *(const bf16x8*)&qb[(size_t)qrow * HEAD + quad * 8];
        a_q1 = *(const bf16x8*)&qb[(size_t)qrow * HEAD + 32 + quad * 8];
    }

    // ---- single-slab staging: 4 chunks of K and V, no guards ----
    // K: thread covers token kt (tid>>2) cols kh8..kh8+15 -> contiguous 2KB/wave
    // V: thread covers h-row  (tid>>2) tokens kh8..kh8+15 of each chunk
    {
        const int kt  = tid >> 2;          // 0..63
        const int kh8 = (tid & 3) * 16;    // 0,16,32,48
#pragma unroll
        for (int cc = 0; cc < 4; cc++) {
            const int t0 = (c0 + cc) * 64; // chunk index <= 31 always: in-range
            bf16x8 k0 = *(const bf16x8*)&kb[(size_t)(t0 + kt) * HEAD + kh8];
            bf16x8 k1 = *(const bf16x8*)&kb[(size_t)(t0 + kt) * HEAD + kh8 + 8];
            *(bf16x8*)&ksh[cc * 64 + kt][kh8]     = k0;
            *(bf16x8*)&ksh[cc * 64 + kt][kh8 + 8] = k1;
            bf16x8 v0 = *(const bf16x8*)&vtb[((size_t)kt << 11) + t0 + kh8];
            bf16x8 v1 = *(const bf16x8*)&vtb[((size_t)kt << 11) + t0 + kh8 + 8];
            *(bf16x8*)&vsh[kt][cc * 64 + kh8]     = v0;
            *(bf16x8*)&vsh[kt][cc * 64 + kh8 + 8] = v1;
        }
    }
    __syncthreads();                   // the ONLY barrier

    f32x4 o_acc[4];
#pragma unroll
    for (int i = 0; i < 4; i++) o_acc[i] = (f32x4){0.f, 0.f, 0.f, 0.f};
    float lsum[4] = {0.f, 0.f, 0.f, 0.f};

    for (int cc = 0; cc < nch; cc++) {
        const int c  = c0 + cc;
        const int t0 = c * 64;

        // ---- QK^T from LDS ----
        f32x4 s_t[4];
#pragma unroll
        for (int nt = 0; nt < 4; nt++) {
            bf16x8 bk0 = *(const bf16x8*)&ksh[cc * 64 + nt * 16 + m16][quad * 8];
            bf16x8 bk1 = *(const bf16x8*)&ksh[cc * 64 + nt * 16 + m16][32 + quad * 8];
            f32x4 acc = (f32x4){0.f, 0.f, 0.f, 0.f};
            acc = __builtin_amdgcn_mfma_f32_16x16x32_bf16(a_q0, bk0, acc, 0, 0, 0);
            acc = __builtin_amdgcn_mfma_f32_16x16x32_bf16(a_q1, bk1, acc, 0, 0, 0);
            s_t[nt] = acc;
        }

        // ---- no-max softmax; mask only on the diagonal chunk (c == qt) ----
        if (c == qt) {
#pragma unroll
            for (int r = 0; r < 4; r++) {
                const int row = qt * 64 + wave * 16 + quad * 4 + r;
#pragma unroll
                for (int nt = 0; nt < 4; nt++) {
                    int tt = t0 + nt * 16 + m16;
                    float p = (tt <= row) ? __expf(s_t[nt][r] * scale) : 0.f;
                    lsum[r] += p;
                    psh[wave][quad * 4 + r][nt * 16 + m16] = f2bf(p);
                }
            }
        } else {
#pragma unroll
            for (int r = 0; r < 4; r++) {
#pragma unroll
                for (int nt = 0; nt < 4; nt++) {
                    float p = __expf(s_t[nt][r] * scale);
                    lsum[r] += p;
                    psh[wave][quad * 4 + r][nt * 16 + m16] = f2bf(p);
                }
            }
        }
        // psh wave-private: in-wave LDS ordering suffices, no barrier.

        // ---- PV: B-frags natural from vsh[h][t'] ----
#pragma unroll
        for (int ss = 0; ss < 2; ss++) {
            bf16x8 a_p = *(const bf16x8*)&psh[wave][m16][ss * 32 + quad * 8];
#pragma unroll
            for (int ht = 0; ht < 4; ht++) {
                bf16x8 b_v = *(const bf16x8*)&vsh[ht * 16 + m16][cc * 64 + ss * 32 + quad * 8];
                o_acc[ht] = __builtin_amdgcn_mfma_f32_16x16x32_bf16(a_p, b_v, o_acc[ht], 0, 0, 0);
            }
        }
    }

    // ---- epilogue: reduce l over 16-lane groups, write partials ----
#pragma unroll
    for (int r = 0; r < 4; r++) {
#pragma unroll
        for (int off = 8; off >= 1; off >>= 1)
            lsum[r] += __shfl_xor(lsum[r], off, 64);
    }
    const size_t slot  = (size_t)b * NSLOT + triOff(qt) + seg;
    const size_t pbase = slot * 64;
#pragma unroll
    for (int ht = 0; ht < 4; ht++) {
#pragma unroll
        for (int r = 0; r < 4; r++) {
            int rowt = wave * 16 + quad * 4 + r;
            pO[(pbase + rowt) * 64 + ht * 16 + m16] = f2bf(o_acc[ht][r]);
        }
    }
    if (m16 == 0) {
#pragma unroll
        for (int r = 0; r < 4; r++) {
            int rowt = wave * 16 + quad * 4 + r;
            pl[pbase + rowt] = lsum[r];
        }
    }
}

// ---------------------------------------------------------------------------
// Kernel 3: combine split-K partials: out = (sum_s O_s) / (sum_s l_s).
// ---------------------------------------------------------------------------
__global__ __launch_bounds__(256) void combine_kernel(
    const short* __restrict__ pO, const float* __restrict__ pl,
    float* __restrict__ out)
{
    int g   = blockIdx.x * 256 + threadIdx.x;   // 262144
    int h4  = (g & 15) * 4;
    int row = (g >> 4) & 2047;
    int b   = g >> 15;
    int qt  = row >> 6, lr = row & 63;
    int ns  = (qt >> 2) + 1;
    size_t base = (size_t)b * NSLOT + triOff(qt);
    float4 O = {0.f, 0.f, 0.f, 0.f};
    float  L = 0.f;
    for (int s = 0; s < ns; s++) {
        bf16x4 ov = *(const bf16x4*)&pO[((base + s) * 64 + lr) * 64 + h4];
        O.x += bf2f(ov[0]); O.y += bf2f(ov[1]);
        O.z += bf2f(ov[2]); O.w += bf2f(ov[3]);
        L += pl[(base + s) * 64 + lr];
    }
    float inv = 1.f / L;
    O.x *= inv; O.y *= inv; O.z *= inv; O.w *= inv;
    *(float4*)&out[(size_t)g * 4] = O;
}

// ---------------------------------------------------------------------------
extern "C" void kernel_launch(void* const* d_in, const int* in_sizes, int n_in,
                              void* d_out, int out_size, void* d_ws, size_t ws_size,
                              hipStream_t stream) {
    const float* x  = (const float*)d_in[0];
    const float* Wq = (const float*)d_in[1];
    const float* Wk = (const float*)d_in[2];
    const float* Wv = (const float*)d_in[3];
    float* out = (float*)d_out;

    short* q  = (short*)d_ws;                       // 1,048,576
    short* k  = q + (size_t)NROWS * HEAD;           // 1,048,576
    short* vt = k + (size_t)NROWS * HEAD;           // 1,048,576 (transposed)
    short* wt = vt + (size_t)NROWS * HEAD;          //   196,608
    short* pO = wt + 196608;                        // 8*144*64*64 = 4,718,592
    float* pl = (float*)(pO + (size_t)BATCH * NSLOT * 64 * 64);  // 73,728

    prep_w<<<96, 256, 0, stream>>>(Wq, Wk, Wv, wt);
    proj_kernel<<<512, 512, 0, stream>>>(x, wt, q, k, vt);
    attn_kernel<<<dim3(32, 8, 8), 256, 0, stream>>>(q, k, vt, pO, pl);
    combine_kernel<<<1024, 256, 0, stream>>>(pO, pl, out);
}

// Round 12
// 128.432 us; speedup vs baseline: 2.6153x; 1.0374x over previous
//
#include <hip/hip_runtime.h>
#include <hip/hip_bf16.h>
#include <math.h>

#define BATCH 8
#define SEQ 2048
#define EMBED 1024
#define HEAD 64
#define NROWS (BATCH*SEQ)   // 16384

typedef short bf16x8 __attribute__((ext_vector_type(8)));
typedef short bf16x4 __attribute__((ext_vector_type(4)));
typedef float f32x4  __attribute__((ext_vector_type(4)));

__device__ inline short f2bf(float f) {
    __hip_bfloat16 h = __float2bfloat16(f);
    return *(short*)&h;
}
__device__ inline float bf2f(short s) {
    __hip_bfloat16 h = *(__hip_bfloat16*)&s;
    return __bfloat162float(h);
}

// Dense triangular slots, 64-row qt tiles, 4-chunk segments:
// slots(qt) = (qt>>2)+1; triOff(qt) = 2g(g+1)+(qt&3)(g+1), g=qt>>2. 144/batch.
#define NSLOT 144
__device__ __host__ inline int triOff(int qt) {
    int g = qt >> 2;
    return 2 * g * (g + 1) + (qt & 3) * (g + 1);
}

// ---------------------------------------------------------------------------
// Kernel 0: W -> bf16 B-fragment order for 16x16x32 MFMA.
// ---------------------------------------------------------------------------
__global__ __launch_bounds__(256) void prep_w(
    const float* __restrict__ Wq, const float* __restrict__ Wk,
    const float* __restrict__ Wv, short* __restrict__ wt)
{
    int g    = blockIdx.x * 256 + threadIdx.x;   // 24576 total
    int lane = g & 63;
    int frag = g >> 6;           // ct*32 + k32
    int k32  = frag & 31;
    int ct   = frag >> 5;        // 0..11
    int col  = ct * 16 + (lane & 15);
    int mm   = col >> 6, cc = col & 63;
    const float* W = (mm == 0) ? Wq : ((mm == 1) ? Wk : Wv);
    int kb = k32 * 32 + (lane >> 4) * 8;
    bf16x8 o;
#pragma unroll
    for (int j = 0; j < 8; j++)
        o[j] = f2bf(W[(size_t)(kb + j) * HEAD + cc]);
    *(bf16x8*)&wt[(size_t)g * 8] = o;
}

// ---------------------------------------------------------------------------
// Kernel 1: QKV projection (single-stage slab, proven R7). V written
// TRANSPOSED per batch: vt[b][h][t].
// ---------------------------------------------------------------------------
__global__ __launch_bounds__(512, 4) void proj_kernel(
    const float* __restrict__ x, const short* __restrict__ wt,
    short* __restrict__ q, short* __restrict__ k, short* __restrict__ vt)
{
    __shared__ short xs[32][1024];   // 64 KB, XOR-swizzled k8 blocks
    float* psum = (float*)&xs[0][0]; // reuse after compute barrier

    const int tid  = threadIdx.x;
    const int wave = tid >> 6, lane = tid & 63;
    const int m16  = lane & 15, quad = lane >> 4;
    const int cg   = wave & 3;
    const int kh   = wave >> 2;
    const int r0   = blockIdx.x * 32;

    {
        const int row  = tid >> 4;
        const int col4 = tid & 15;
        const float* xr = x + (size_t)(r0 + row) * EMBED;
#pragma unroll
        for (int h = 0; h < 2; h++) {
            float4 f[8];
#pragma unroll
            for (int i = 0; i < 8; i++)
                f[i] = *(const float4*)&xr[(h * 8 + i) * 64 + col4 * 4];
#pragma unroll
            for (int i = 0; i < 8; i++) {
                int c  = (h * 8 + i) * 64 + col4 * 4;
                int k8 = c >> 3, rem = c & 7;
                int cs = ((k8 ^ (row & 7)) << 3) + rem;
                bf16x4 bv;
                bv[0] = f2bf(f[i].x); bv[1] = f2bf(f[i].y);
                bv[2] = f2bf(f[i].z); bv[3] = f2bf(f[i].w);
                *(bf16x4*)&xs[row][cs] = bv;
            }
        }
    }
    __syncthreads();

    f32x4 acc[2][3];
#pragma unroll
    for (int mt = 0; mt < 2; mt++)
#pragma unroll
        for (int j = 0; j < 3; j++) acc[mt][j] = (f32x4){0.f, 0.f, 0.f, 0.f};

#pragma unroll 4
    for (int s = 0; s < 16; s++) {
        int k32  = kh * 16 + s;
        int ksw  = ((k32 * 4 + quad) ^ (m16 & 7)) << 3;
        bf16x8 a0 = *(const bf16x8*)&xs[m16][ksw];
        bf16x8 a1 = *(const bf16x8*)&xs[16 + m16][ksw];
#pragma unroll
        for (int j = 0; j < 3; j++) {
            int ct = cg * 3 + j;
            bf16x8 bb = *(const bf16x8*)&wt[(size_t)((ct * 32 + k32) * 64 + lane) * 8];
            acc[0][j] = __builtin_amdgcn_mfma_f32_16x16x32_bf16(a0, bb, acc[0][j], 0, 0, 0);
            acc[1][j] = __builtin_amdgcn_mfma_f32_16x16x32_bf16(a1, bb, acc[1][j], 0, 0, 0);
        }
    }

    __syncthreads();
    if (kh == 1) {
        float* p = psum + ((size_t)(cg * 64 + lane) * 24);
#pragma unroll
        for (int mt = 0; mt < 2; mt++)
#pragma unroll
            for (int j = 0; j < 3; j++)
                *(f32x4*)&p[(mt * 3 + j) * 4] = acc[mt][j];
    }
    __syncthreads();
    if (kh == 0) {
        const float* p = psum + ((size_t)(cg * 64 + lane) * 24);
        const int bb = r0 >> 11;
        const int tb = r0 & 2047;
#pragma unroll
        for (int mt = 0; mt < 2; mt++)
#pragma unroll
            for (int j = 0; j < 3; j++) {
                f32x4 o = acc[mt][j] + *(const f32x4*)&p[(mt * 3 + j) * 4];
                int gcol = (cg * 3 + j) * 16 + m16;
                int mm = gcol >> 6, cc = gcol & 63;
                if (mm < 2) {
                    short* op = (mm == 0) ? q : k;
#pragma unroll
                    for (int reg = 0; reg < 4; reg++) {
                        int row = r0 + mt * 16 + quad * 4 + reg;
                        op[(size_t)row * HEAD + cc] = f2bf(o[reg]);
                    }
                } else {
                    bf16x4 pk;
                    pk[0] = f2bf(o[0]); pk[1] = f2bf(o[1]);
                    pk[2] = f2bf(o[2]); pk[3] = f2bf(o[3]);
                    int t = tb + mt * 16 + quad * 4;
                    *(bf16x4*)&vt[(((size_t)bb * 64 + cc) << 11) + t] = pk;
                }
            }
    }
}

// ---------------------------------------------------------------------------
// Kernel 2: split-K flash attention, R6/R7-proven 2-barrier skeleton with
// occupancy bump: stride-72 LDS (27 KB -> 5 blocks/CU = 20 waves/CU) and
// V staged natural from pre-transposed vt (no pack/swizzle VALU).
// Grid (qt=32, seg=8, b=8); 256 thr; register prefetch after barrier B;
// no-max softmax; diagonal-only causal mask; dense triangular partials.
// ---------------------------------------------------------------------------
__global__ __launch_bounds__(256, 5) void attn_kernel(
    const short* __restrict__ qg, const short* __restrict__ kg,
    const short* __restrict__ vtg,
    short* __restrict__ pO, float* __restrict__ pl)
{
    __shared__ short ksh[64][72];      // [t][h]   9216 B
    __shared__ short vsh[64][72];      // [h][t]   9216 B (from vt, natural)
    __shared__ short psh[4][16][72];   // [wave][row][t] 9216 B, wave-private

    const int qt  = blockIdx.x;        // 0..31
    const int seg = blockIdx.y;        // 0..7
    const int b   = blockIdx.z;
    const int c0  = seg * 4;
    const int c1  = min(seg * 4 + 4, qt + 1);
    if (c0 >= c1) return;

    const int tid  = threadIdx.x;
    const int wave = tid >> 6, lane = tid & 63;
    const int m16  = lane & 15, quad = lane >> 4;
    const float scale = 0.03125f;      // 1024^-0.5

    const short* qb  = qg  + (size_t)b * SEQ * HEAD;
    const short* kb  = kg  + (size_t)b * SEQ * HEAD;
    const short* vtb = vtg + (size_t)b * HEAD * SEQ;

    bf16x8 a_q0, a_q1;
    {
        const int qrow = qt * 64 + wave * 16 + m16;
        a_q0 = *(const bf16x8*)&qb[(size_t)qrow * HEAD + quad * 8];
        a_q1 = *(const bf16x8*)&qb[(size_t)qrow * HEAD + 32 + quad * 8];
    }

    f32x4 o_acc[4];
#pragma unroll
    for (int i = 0; i < 4; i++) o_acc[i] = (f32x4){0.f, 0.f, 0.f, 0.f};
    float lsum[4] = {0.f, 0.f, 0.f, 0.f};

    // staging: thread owns two 16B segments of K and two of V (rows r, r+32)
    const int srow = tid >> 3;         // 0..31
    const int sc8  = (tid & 7) * 8;    // 0..56

    bf16x8 kr0 = *(const bf16x8*)&kb[(size_t)(c0 * 64 + srow) * HEAD + sc8];
    bf16x8 kr1 = *(const bf16x8*)&kb[(size_t)(c0 * 64 + 32 + srow) * HEAD + sc8];
    bf16x8 vr0 = *(const bf16x8*)&vtb[((size_t)srow << 11) + c0 * 64 + sc8];
    bf16x8 vr1 = *(const bf16x8*)&vtb[((size_t)(srow + 32) << 11) + c0 * 64 + sc8];

    for (int c = c0; c < c1; c++) {
        const int t0 = c * 64;
        __syncthreads();               // barrier A: prev-iter LDS readers done
        *(bf16x8*)&ksh[srow][sc8]      = kr0;
        *(bf16x8*)&ksh[srow + 32][sc8] = kr1;
        *(bf16x8*)&vsh[srow][sc8]      = vr0;
        *(bf16x8*)&vsh[srow + 32][sc8] = vr1;
        __syncthreads();               // barrier B: stores visible
        if (c + 1 < c1) {              // prefetch next chunk (overlaps compute)
            const int tn = (c + 1) * 64;
            kr0 = *(const bf16x8*)&kb[(size_t)(tn + srow) * HEAD + sc8];
            kr1 = *(const bf16x8*)&kb[(size_t)(tn + 32 + srow) * HEAD + sc8];
            vr0 = *(const bf16x8*)&vtb[((size_t)srow << 11) + tn + sc8];
            vr1 = *(const bf16x8*)&vtb[((size_t)(srow + 32) << 11) + tn + sc8];
        }

        // ---- QK^T from LDS ----
        f32x4 s_t[4];
#pragma unroll
        for (int nt = 0; nt < 4; nt++) {
            bf16x8 bk0 = *(const bf16x8*)&ksh[nt * 16 + m16][quad * 8];
            bf16x8 bk1 = *(const bf16x8*)&ksh[nt * 16 + m16][32 + quad * 8];
            f32x4 acc = (f32x4){0.f, 0.f, 0.f, 0.f};
            acc = __builtin_amdgcn_mfma_f32_16x16x32_bf16(a_q0, bk0, acc, 0, 0, 0);
            acc = __builtin_amdgcn_mfma_f32_16x16x32_bf16(a_q1, bk1, acc, 0, 0, 0);
            s_t[nt] = acc;
        }

        // ---- no-max softmax; mask only on the diagonal chunk ----
        if (c == qt) {
#pragma unroll
            for (int r = 0; r < 4; r++) {
                const int row = qt * 64 + wave * 16 + quad * 4 + r;
#pragma unroll
                for (int nt = 0; nt < 4; nt++) {
                    int tt = t0 + nt * 16 + m16;
                    float p = (tt <= row) ? __expf(s_t[nt][r] * scale) : 0.f;
                    lsum[r] += p;
                    psh[wave][quad * 4 + r][nt * 16 + m16] = f2bf(p);
                }
            }
        } else {
#pragma unroll
            for (int r = 0; r < 4; r++) {
#pragma unroll
                for (int nt = 0; nt < 4; nt++) {
                    float p = __expf(s_t[nt][r] * scale);
                    lsum[r] += p;
                    psh[wave][quad * 4 + r][nt * 16 + m16] = f2bf(p);
                }
            }
        }
        // psh wave-private: in-wave LDS ordering suffices, no barrier.

        // ---- PV: B-frags natural from vsh[h][t] ----
#pragma unroll
        for (int ss = 0; ss < 2; ss++) {
            bf16x8 a_p = *(const bf16x8*)&psh[wave][m16][ss * 32 + quad * 8];
#pragma unroll
            for (int ht = 0; ht < 4; ht++) {
                bf16x8 b_v = *(const bf16x8*)&vsh[ht * 16 + m16][ss * 32 + quad * 8];
                o_acc[ht] = __builtin_amdgcn_mfma_f32_16x16x32_bf16(a_p, b_v, o_acc[ht], 0, 0, 0);
            }
        }
    }

    // ---- epilogue: reduce l over 16-lane groups, write partials ----
#pragma unroll
    for (int r = 0; r < 4; r++) {
#pragma unroll
        for (int off = 8; off >= 1; off >>= 1)
            lsum[r] += __shfl_xor(lsum[r], off, 64);
    }
    const size_t slot  = (size_t)b * NSLOT + triOff(qt) + seg;
    const size_t pbase = slot * 64;
#pragma unroll
    for (int ht = 0; ht < 4; ht++) {
#pragma unroll
        for (int r = 0; r < 4; r++) {
            int rowt = wave * 16 + quad * 4 + r;
            pO[(pbase + rowt) * 64 + ht * 16 + m16] = f2bf(o_acc[ht][r]);
        }
    }
    if (m16 == 0) {
#pragma unroll
        for (int r = 0; r < 4; r++) {
            int rowt = wave * 16 + quad * 4 + r;
            pl[pbase + rowt] = lsum[r];
        }
    }
}

// ---------------------------------------------------------------------------
// Kernel 3: combine split-K partials: out = (sum_s O_s) / (sum_s l_s).
// ---------------------------------------------------------------------------
__global__ __launch_bounds__(256) void combine_kernel(
    const short* __restrict__ pO, const float* __restrict__ pl,
    float* __restrict__ out)
{
    int g   = blockIdx.x * 256 + threadIdx.x;   // 262144
    int h4  = (g & 15) * 4;
    int row = (g >> 4) & 2047;
    int b   = g >> 15;
    int qt  = row >> 6, lr = row & 63;
    int ns  = (qt >> 2) + 1;
    size_t base = (size_t)b * NSLOT + triOff(qt);
    float4 O = {0.f, 0.f, 0.f, 0.f};
    float  L = 0.f;
    for (int s = 0; s < ns; s++) {
        bf16x4 ov = *(const bf16x4*)&pO[((base + s) * 64 + lr) * 64 + h4];
        O.x += bf2f(ov[0]); O.y += bf2f(ov[1]);
        O.z += bf2f(ov[2]); O.w += bf2f(ov[3]);
        L += pl[(base + s) * 64 + lr];
    }
    float inv = 1.f / L;
    O.x *= inv; O.y *= inv; O.z *= inv; O.w *= inv;
    *(float4*)&out[(size_t)g * 4] = O;
}

// ---------------------------------------------------------------------------
extern "C" void kernel_launch(void* const* d_in, const int* in_sizes, int n_in,
                              void* d_out, int out_size, void* d_ws, size_t ws_size,
                              hipStream_t stream) {
    const float* x  = (const float*)d_in[0];
    const float* Wq = (const float*)d_in[1];
    const float* Wk = (const float*)d_in[2];
    const float* Wv = (const float*)d_in[3];
    float* out = (float*)d_out;

    short* q  = (short*)d_ws;                       // 1,048,576
    short* k  = q + (size_t)NROWS * HEAD;           // 1,048,576
    short* vt = k + (size_t)NROWS * HEAD;           // 1,048,576 (transposed)
    short* wt = vt + (size_t)NROWS * HEAD;          //   196,608
    short* pO = wt + 196608;                        // 8*144*64*64 = 4,718,592
    float* pl = (float*)(pO + (size_t)BATCH * NSLOT * 64 * 64);  // 73,728

    prep_w<<<96, 256, 0, stream>>>(Wq, Wk, Wv, wt);
    proj_kernel<<<512, 512, 0, stream>>>(x, wt, q, k, vt);
    attn_kernel<<<dim3(32, 8, 8), 256, 0, stream>>>(q, k, vt, pO, pl);
    combine_kernel<<<1024, 256, 0, stream>>>(pO, pl, out);
}